// Round 18
// baseline (395.690 us; speedup 1.0000x reference)
//
#include <hip/hip_runtime.h>
#include <math.h>

// Problem constants (B=4, L=1024, D=1024, H=16, DK=64)
#define NB 4
#define NL 1024
#define ND 1024
#define NH 16
#define NDK 64

// ATTRIBUTION ROUND 2: reps on the two never-measured kernels.
#define PREP_REPS 16
#define OUTP_REPS 24

typedef __attribute__((ext_vector_type(8))) short short8;
typedef __attribute__((ext_vector_type(4))) float f32x4;

__device__ inline ushort f2bf(float f) {
    uint x = __float_as_uint(f);
    x += 0x7FFFu + ((x >> 16) & 1u);   // RNE
    return (ushort)(x >> 16);
}
__device__ inline float bf2f(ushort u) { return __uint_as_float(((uint)u) << 16); }

__device__ inline void gload16(const void* g, void* l) {
    __builtin_amdgcn_global_load_lds(
        (const __attribute__((address_space(1))) void*)g,
        (__attribute__((address_space(3))) void*)l, 16, 0, 0);
}

// ---------------------------------------------------------------------------
// Prep: input bf16 cvt (blocks 0..6143) + weight cvt/transpose (6144..6671).
// Wrapped in PREP_REPS idempotent repeats for attribution.
// ---------------------------------------------------------------------------
__global__ __launch_bounds__(256) void prep_kernel(
    const float* __restrict__ q, const float* __restrict__ k,
    const float* __restrict__ v,
    const float* __restrict__ wq, const float* __restrict__ wk,
    const float* __restrict__ wv,
    ushort* __restrict__ abf,
    ushort* __restrict__ wqT, ushort* __restrict__ wkT, ushort* __restrict__ wvT)
{
    __shared__ ushort tl[64][72];
    const int t = threadIdx.x;
    const int bid = blockIdx.x;

    for (int rep = 0; rep < PREP_REPS; ++rep) {
        if (bid < 6144) {
            int y = bid >> 11, x = bid & 2047;
            const float* src = (y == 0) ? q : (y == 1) ? k : v;
            size_t base = ((size_t)x * 256 + t) * 8;
            float4 a = *(const float4*)(src + base);
            float4 b = *(const float4*)(src + base + 4);
            short8 o;
            o[0] = (short)f2bf(a.x); o[1] = (short)f2bf(a.y);
            o[2] = (short)f2bf(a.z); o[3] = (short)f2bf(a.w);
            o[4] = (short)f2bf(b.x); o[5] = (short)f2bf(b.y);
            o[6] = (short)f2bf(b.z); o[7] = (short)f2bf(b.w);
            *(short8*)(abf + (size_t)y * (NB * NL * ND) + base) = o;
            __syncthreads();   // rep boundary (keeps loop material)
            continue;
        }

        int id = bid - 6144;
        int d0 = (id & 15) * 64;
        int y = id >> 4;
        const float* src; ushort* dst; int h;
        if (y < 16)      { src = wq + (size_t)y * ND * NDK;        dst = wqT; h = y; }
        else if (y < 32) { src = wk + (size_t)(y - 16) * ND * NDK; dst = wkT; h = y - 16; }
        else             { src = wv;                               dst = wvT; h = 0; }

        int r = t >> 2, c0 = (t & 3) * 16;
        const float* s = src + (size_t)(d0 + r) * NDK + c0;
        #pragma unroll
        for (int j = 0; j < 16; j += 4) {
            float4 vv4 = *(const float4*)(s + j);
            tl[c0 + j + 0][r] = f2bf(vv4.x);
            tl[c0 + j + 1][r] = f2bf(vv4.y);
            tl[c0 + j + 2][r] = f2bf(vv4.z);
            tl[c0 + j + 3][r] = f2bf(vv4.w);
        }
        __syncthreads();
        int vv = t >> 2, lc = (t & 3) * 16;
        ushort* d = dst + ((size_t)h * 64 + vv) * ND + d0 + lc;
        #pragma unroll
        for (int j = 0; j < 16; j += 8) {
            short8 o;
            #pragma unroll
            for (int e = 0; e < 8; ++e) o[e] = (short)tl[vv][lc + j + e];
            *(short8*)(d + j) = o;
        }
        if (y == 32) {
            ushort* zp = wvT + ((size_t)(64 + (t >> 2))) * ND + d0 + (t & 3) * 16;
            short8 z8 = {0,0,0,0,0,0,0,0};
            *(short8*)(zp) = z8;
            *(short8*)(zp + 8) = z8;
        }
        __syncthreads();   // rep boundary: tl readers done before re-write
    }
}

// ---------------------------------------------------------------------------
// MFMA projection GEMM (exact r16). BM=64 x BN=128, BK=64, 4 waves.
// ---------------------------------------------------------------------------
__global__ __launch_bounds__(256) void proj_gemm(
    const ushort* __restrict__ abf,
    const ushort* __restrict__ wqT, const ushort* __restrict__ wkT,
    const ushort* __restrict__ wvT,
    const float* __restrict__ bq, const float* __restrict__ bk,
    const float* __restrict__ bv,
    ushort* __restrict__ q_all, ushort* __restrict__ k_all,
    ushort* __restrict__ vT)
{
    __shared__ char lds[49152];   // buf c at c*24576: A [64][64] @0, B [128][64] @8192

    int id = blockIdx.x;
    int wg = (id & 7) * 136 + (id >> 3);   // 1088 = 8 XCDs x 136, bijective
    int z, mt, nt;
    if (wg < 512)       { z = 0; mt = wg >> 3; nt = wg & 7; }
    else if (wg < 1024) { z = 1; int r2 = wg - 512; mt = r2 >> 3; nt = r2 & 7; }
    else                { z = 2; mt = wg - 1024; nt = 0; }

    const ushort* A; const ushort* Bw; const float* bias; float scale;
    if (z == 0)      { A = abf;                    Bw = wqT; bias = bq; scale = 0.125f; }
    else if (z == 1) { A = abf + NB * NL * ND;     Bw = wkT; bias = bk; scale = 1.0f; }
    else             { A = abf + 2 * NB * NL * ND; Bw = wvT; bias = bv; scale = 1.0f; }
    ushort* C = (z == 0) ? q_all : k_all;

    const int t = threadIdx.x;
    const int w = t >> 6, l = t & 63;
    const int lo16 = l & 15, hi = l >> 4;
    const int wm = w >> 1, wn = w & 1;     // wave tile: rows wm*32, cols wn*64
    const int m0 = mt * 64, n0 = nt * 128;

    f32x4 acc[2][4];
    #pragma unroll
    for (int mi = 0; mi < 2; ++mi)
        #pragma unroll
        for (int ni = 0; ni < 4; ++ni) acc[mi][ni] = (f32x4){0.f, 0.f, 0.f, 0.f};

    const int lrow = l >> 3;
    const uint lcol = ((uint)(l & 7) * 16u) ^ (((uint)lrow) << 4);

    #pragma unroll
    for (int i = 0; i < 2; ++i) {
        int s = w * 2 + i;
        gload16(A + (size_t)(m0 + s * 8 + lrow) * ND + (lcol >> 1), lds + s * 1024);
    }
    #pragma unroll
    for (int i = 0; i < 4; ++i) {
        int s = w * 4 + i;
        gload16(Bw + (size_t)(n0 + s * 8 + lrow) * ND + (lcol >> 1), lds + 8192 + s * 1024);
    }
    __syncthreads();

    int cur = 0;
    for (int kt = 0; kt < 16; ++kt) {
        if (kt < 15) {
            const int k1 = (kt + 1) * 64;
            const int nb = (cur ^ 1) * 24576;
            #pragma unroll
            for (int i = 0; i < 2; ++i) {
                int s = w * 2 + i;
                gload16(A + (size_t)(m0 + s * 8 + lrow) * ND + k1 + (lcol >> 1), lds + nb + s * 1024);
            }
            #pragma unroll
            for (int i = 0; i < 4; ++i) {
                int s = w * 4 + i;
                gload16(Bw + (size_t)(n0 + s * 8 + lrow) * ND + k1 + (lcol >> 1), lds + nb + 8192 + s * 1024);
            }
        }
        const int cb = cur * 24576;
        #pragma unroll
        for (int ks = 0; ks < 2; ++ks) {
            short8 Af[2], Bf[4];
            #pragma unroll
            for (int mi = 0; mi < 2; ++mi) {
                int row = wm * 32 + mi * 16 + lo16;
                uint off = ((uint)row * 128u + (uint)(ks * 64 + hi * 16)) ^ (((uint)(row & 7)) << 4);
                Af[mi] = *(short8*)(lds + cb + off);
            }
            #pragma unroll
            for (int ni = 0; ni < 4; ++ni) {
                int row = wn * 64 + ni * 16 + lo16;
                uint off = ((uint)row * 128u + (uint)(ks * 64 + hi * 16)) ^ (((uint)(row & 7)) << 4);
                Bf[ni] = *(short8*)(lds + cb + 8192 + off);
            }
            __builtin_amdgcn_s_setprio(1);
            #pragma unroll
            for (int mi = 0; mi < 2; ++mi)
                #pragma unroll
                for (int ni = 0; ni < 4; ++ni)
                    acc[mi][ni] = __builtin_amdgcn_mfma_f32_16x16x32_bf16(
                        Af[mi], Bf[ni], acc[mi][ni], 0, 0, 0);
            __builtin_amdgcn_s_setprio(0);
        }
        __syncthreads();   // drains vmcnt (prefetch landed) + readers done
        cur ^= 1;
    }

    // D frag: row = hi*4 + r (+16*mi), col = lo16 (+16*ni).
    if (z == 2) {
        if (wn == 0) {
            #pragma unroll
            for (int ni = 0; ni < 4; ++ni) {
                int n = ni * 16 + lo16;          // dk 0..63
                float bs = bias[n];
                #pragma unroll
                for (int mi = 0; mi < 2; ++mi) {
                    int mbase = m0 + wm * 32 + mi * 16 + hi * 4;
                    int b = mbase >> 10, ll = mbase & 1023;
                    uint u0 = (uint)f2bf(acc[mi][ni][0] + bs) | ((uint)f2bf(acc[mi][ni][1] + bs) << 16);
                    uint u1 = (uint)f2bf(acc[mi][ni][2] + bs) | ((uint)f2bf(acc[mi][ni][3] + bs) << 16);
                    *(uint2*)(vT + ((size_t)b * NDK + n) * NL + ll) = make_uint2(u0, u1);
                }
            }
        }
        return;
    }

    // z<2: restage C tile in LDS (bf16 [64][128] = 16KB), then short8 stores.
    ushort* cst = (ushort*)lds;
    const int n0w = wn * 64;
    #pragma unroll
    for (int ni = 0; ni < 4; ++ni) {
        int nl = n0w + ni * 16 + lo16;
        float bs = bias[n0 + nl];
        #pragma unroll
        for (int mi = 0; mi < 2; ++mi) {
            int mlb = wm * 32 + mi * 16 + hi * 4;
            #pragma unroll
            for (int r = 0; r < 4; ++r)
                cst[(mlb + r) * 128 + nl] = f2bf((acc[mi][ni][r] + bs) * scale);
        }
    }
    __syncthreads();
    #pragma unroll
    for (int i = 0; i < 4; ++i) {
        int unit = t + 256 * i;               // 0..1023
        int row = unit >> 4, s8 = unit & 15;
        short8 v = *(short8*)(cst + row * 128 + s8 * 8);
        int m = m0 + row, n = n0 + s8 * 8;
        int b = m >> 10, ll = m & 1023, h = n >> 6, dk = n & 63;
        *(short8*)(C + (((size_t)b * NH + h) * NL + ll) * NDK + dk) = v;
    }
}

// ---------------------------------------------------------------------------
// Stage 2: MFMA attention (exact r16: 32-row q-tile, h-major grid, nt
// interleaved writes, stride-68 pvp).
// ---------------------------------------------------------------------------
__global__ __launch_bounds__(256) void attn_mfma_kernel(
    const ushort* __restrict__ q_all, const ushort* __restrict__ k_all,
    const ushort* __restrict__ vT,
    float* __restrict__ attn, ushort* __restrict__ heads)
{
    __shared__ char raw[65536 + 640];
    float* smv  = (float*)(raw + 65536);         // [4][32]
    float* invb = (float*)(raw + 65536 + 512);   // [32]

    const int t = threadIdx.x;
    const int kh = t >> 6, l = t & 63;           // wave = k-quarter
    const int hi = l >> 4, lo = l & 15;
    const int h  = blockIdx.x;
    const int q0 = blockIdx.y * 32;
    const int b  = blockIdx.z;
    const size_t bh = ((size_t)b * NH + h) * NL;

    const int qrA = lo;            // rows 0-15 of tile
    const int qrB = 16 + lo;       // rows 16-31; (16+lo)&7 == lo&7 -> same swz
    const uint swz = ((uint)(lo & 7)) << 4;

    short8 QA0 = *(const short8*)(q_all + (bh + q0 + qrA) * NDK + hi * 8);
    short8 QA1 = *(const short8*)(q_all + (bh + q0 + qrA) * NDK + 32 + hi * 8);
    short8 QB0 = *(const short8*)(q_all + (bh + q0 + qrB) * NDK + hi * 8);
    short8 QB1 = *(const short8*)(q_all + (bh + q0 + qrB) * NDK + 32 + hi * 8);

    // ---- QK^T + exp fused: e -> LDS (bf16), sums in registers ----
    float ssumA = 0.f, ssumB = 0.f;
    for (int kt = 0; kt < 16; ++kt) {
        const int kbase = kh * 256 + kt * 16;
        short8 Ka0 = *(const short8*)(k_all + (bh + kbase + lo) * NDK + hi * 8);
        short8 Ka1 = *(const short8*)(k_all + (bh + kbase + lo) * NDK + 32 + hi * 8);
        f32x4 sA = {0.f, 0.f, 0.f, 0.f};
        f32x4 sB = {0.f, 0.f, 0.f, 0.f};
        __builtin_amdgcn_s_setprio(1);
        sA = __builtin_amdgcn_mfma_f32_16x16x32_bf16(Ka0, QA0, sA, 0, 0, 0);
        sA = __builtin_amdgcn_mfma_f32_16x16x32_bf16(Ka1, QA1, sA, 0, 0, 0);
        sB = __builtin_amdgcn_mfma_f32_16x16x32_bf16(Ka0, QB0, sB, 0, 0, 0);
        sB = __builtin_amdgcn_mfma_f32_16x16x32_bf16(Ka1, QB1, sB, 0, 0, 0);
        __builtin_amdgcn_s_setprio(0);
        float a0 = __expf(sA[0]), a1 = __expf(sA[1]);
        float a2 = __expf(sA[2]), a3 = __expf(sA[3]);
        float b0 = __expf(sB[0]), b1 = __expf(sB[1]);
        float b2 = __expf(sB[2]), b3 = __expf(sB[3]);
        ssumA += (a0 + a1) + (a2 + a3);
        ssumB += (b0 + b1) + (b2 + b3);
        uint colb = (((uint)(kbase + hi * 4)) * 2u) ^ swz;
        *(uint2*)(raw + (uint)qrA * 2048u + colb) =
            make_uint2((uint)f2bf(a0) | ((uint)f2bf(a1) << 16),
                       (uint)f2bf(a2) | ((uint)f2bf(a3) << 16));
        *(uint2*)(raw + (uint)qrB * 2048u + colb) =
            make_uint2((uint)f2bf(b0) | ((uint)f2bf(b1) << 16),
                       (uint)f2bf(b2) | ((uint)f2bf(b3) << 16));
    }
    ssumA += __shfl_xor(ssumA, 16);
    ssumA += __shfl_xor(ssumA, 32);
    ssumB += __shfl_xor(ssumB, 16);
    ssumB += __shfl_xor(ssumB, 32);
    if (l < 16) {
        smv[kh * 32 + l]      = ssumA;
        smv[kh * 32 + 16 + l] = ssumB;
    }
    __syncthreads();
    if (t < 32) invb[t] = 1.0f / (smv[t] + smv[32 + t] + smv[64 + t] + smv[96 + t]);
    __syncthreads();

    // ---- PV with interleaved attn-row nt writes (4 rows per kc iter) ----
    f32x4 accA0 = {0.f,0.f,0.f,0.f}, accA1 = {0.f,0.f,0.f,0.f};
    f32x4 accA2 = {0.f,0.f,0.f,0.f}, accA3 = {0.f,0.f,0.f,0.f};
    f32x4 accB0 = {0.f,0.f,0.f,0.f}, accB1 = {0.f,0.f,0.f,0.f};
    f32x4 accB2 = {0.f,0.f,0.f,0.f}, accB3 = {0.f,0.f,0.f,0.f};
    for (int kc = 0; kc < 8; ++kc) {
        const int kchunk = kh * 256 + kc * 32;
        uint colb = (((uint)(kchunk + hi * 8)) * 2u) ^ swz;
        short8 paA = *(short8*)(raw + (uint)qrA * 2048u + colb);
        short8 paB = *(short8*)(raw + (uint)qrB * 2048u + colb);
        short8 b0 = *(const short8*)(vT + ((size_t)(b * NDK +  0 + lo)) * NL + kchunk + hi * 8);
        short8 b1 = *(const short8*)(vT + ((size_t)(b * NDK + 16 + lo)) * NL + kchunk + hi * 8);
        short8 b2 = *(const short8*)(vT + ((size_t)(b * NDK + 32 + lo)) * NL + kchunk + hi * 8);
        short8 b3 = *(const short8*)(vT + ((size_t)(b * NDK + 48 + lo)) * NL + kchunk + hi * 8);
        __builtin_amdgcn_s_setprio(1);
        accA0 = __builtin_amdgcn_mfma_f32_16x16x32_bf16(paA, b0, accA0, 0, 0, 0);
        accA1 = __builtin_amdgcn_mfma_f32_16x16x32_bf16(paA, b1, accA1, 0, 0, 0);
        accA2 = __builtin_amdgcn_mfma_f32_16x16x32_bf16(paA, b2, accA2, 0, 0, 0);
        accA3 = __builtin_amdgcn_mfma_f32_16x16x32_bf16(paA, b3, accA3, 0, 0, 0);
        accB0 = __builtin_amdgcn_mfma_f32_16x16x32_bf16(paB, b0, accB0, 0, 0, 0);
        accB1 = __builtin_amdgcn_mfma_f32_16x16x32_bf16(paB, b1, accB1, 0, 0, 0);
        accB2 = __builtin_amdgcn_mfma_f32_16x16x32_bf16(paB, b2, accB2, 0, 0, 0);
        accB3 = __builtin_amdgcn_mfma_f32_16x16x32_bf16(paB, b3, accB3, 0, 0, 0);
        __builtin_amdgcn_s_setprio(0);
        // independent of the MFMAs above: stream 4 normalized attn rows
        #pragma unroll
        for (int rj = 0; rj < 4; ++rj) {
            int rr = kc * 4 + rj;
            uint byteoff = (uint)rr * 2048u + (((uint)t * 8u) ^ (((uint)(rr & 7)) << 4));
            uint2 v = *(uint2*)(raw + byteoff);
            float inv = invb[rr];
            f32x4 o;
            o[0] = bf2f((ushort)(v.x & 0xFFFF)) * inv;
            o[1] = bf2f((ushort)(v.x >> 16)) * inv;
            o[2] = bf2f((ushort)(v.y & 0xFFFF)) * inv;
            o[3] = bf2f((ushort)(v.y >> 16)) * inv;
            __builtin_nontemporal_store(o,
                (f32x4*)(attn + (((size_t)b * NL + q0 + rr) * NH + h) * NL + (size_t)t * 4));
        }
    }
    __syncthreads();   // all waves done READING e before aliasing writes
    float* pvp = (float*)raw;   // [4 kh][32 q] rows, stride 68 words (34.8KB)
    #pragma unroll
    for (int r = 0; r < 4; ++r) {
        int rowA = kh * 32 + hi * 4 + r;
        pvp[rowA * 68 +  0 + lo] = accA0[r];
        pvp[rowA * 68 + 16 + lo] = accA1[r];
        pvp[rowA * 68 + 32 + lo] = accA2[r];
        pvp[rowA * 68 + 48 + lo] = accA3[r];
        int rowB = rowA + 16;
        pvp[rowB * 68 +  0 + lo] = accB0[r];
        pvp[rowB * 68 + 16 + lo] = accB1[r];
        pvp[rowB * 68 + 32 + lo] = accB2[r];
        pvp[rowB * 68 + 48 + lo] = accB3[r];
    }
    __syncthreads();
    #pragma unroll
    for (int i = 0; i < 8; ++i) {
        int idx = t + 256 * i;              // 0..2047 = qq*64 + vv
        int qq = idx >> 6, vv = idx & 63;
        float s4 = pvp[qq * 68 + vv] + pvp[(32 + qq) * 68 + vv]
                 + pvp[(64 + qq) * 68 + vv] + pvp[(96 + qq) * 68 + vv];
        heads[(bh + q0 + qq) * NDK + vv] = f2bf(s4 * invb[qq]);
    }
}

// ---------------------------------------------------------------------------
// Stage 3: head-mean (inline, bf16 heads) + output projection.
// Wrapped in OUTP_REPS idempotent repeats for attribution.
// ---------------------------------------------------------------------------
__global__ __launch_bounds__(256) void out_proj_kernel(
    const ushort* __restrict__ heads, const float* __restrict__ wo,
    const float* __restrict__ bo, float* __restrict__ out)
{
    const int t = threadIdx.x;
    const int row0 = blockIdx.x * 8;          // global row (b*1024 + l)
    const int b = row0 >> 10, l0 = row0 & 1023;
    __shared__ float hm[8][64];

    for (int rep = 0; rep < OUTP_REPS; ++rep) {
        if (t < 128) {
            int r = t >> 4;
            int f4 = t & 15;
            float sx = 0.f, sy = 0.f, sz = 0.f, sw = 0.f;
            #pragma unroll
            for (int h = 0; h < 16; ++h) {
                uint2 v = *(const uint2*)&heads[(((size_t)b * NH + h) * NL + l0 + r) * NDK + f4 * 4];
                sx += bf2f((ushort)(v.x & 0xFFFF));
                sy += bf2f((ushort)(v.x >> 16));
                sz += bf2f((ushort)(v.y & 0xFFFF));
                sw += bf2f((ushort)(v.y >> 16));
            }
            float4 o; o.x = sx * 0.0625f; o.y = sy * 0.0625f; o.z = sz * 0.0625f; o.w = sw * 0.0625f;
            *(float4*)&hm[r][f4 * 4] = o;
        }
        __syncthreads();

        float acc[8][4];
        #pragma unroll
        for (int r = 0; r < 8; ++r)
            #pragma unroll
            for (int j = 0; j < 4; ++j) acc[r][j] = 0.f;

        for (int k = 0; k < 64; ++k) {
            float w0 = wo[(size_t)k * ND + t];
            float w1 = wo[(size_t)k * ND + t + 256];
            float w2 = wo[(size_t)k * ND + t + 512];
            float w3 = wo[(size_t)k * ND + t + 768];
            #pragma unroll
            for (int r = 0; r < 8; ++r) {
                float hv = hm[r][k];
                acc[r][0] += hv * w0;
                acc[r][1] += hv * w1;
                acc[r][2] += hv * w2;
                acc[r][3] += hv * w3;
            }
        }
        #pragma unroll
        for (int r = 0; r < 8; ++r) {
            out[((size_t)row0 + r) * ND + t      ] = acc[r][0] + bo[t];
            out[((size_t)row0 + r) * ND + t + 256] = acc[r][1] + bo[t + 256];
            out[((size_t)row0 + r) * ND + t + 512] = acc[r][2] + bo[t + 512];
            out[((size_t)row0 + r) * ND + t + 768] = acc[r][3] + bo[t + 768];
        }
        __syncthreads();   // rep boundary: hm readers done before re-write
    }
}

// ---------------------------------------------------------------------------
extern "C" void kernel_launch(void* const* d_in, const int* in_sizes, int n_in,
                              void* d_out, int out_size, void* d_ws, size_t ws_size,
                              hipStream_t stream) {
    const float* query  = (const float*)d_in[0];
    const float* key_in = (const float*)d_in[1];
    const float* value  = (const float*)d_in[2];
    const float* wq     = (const float*)d_in[3];
    const float* bq     = (const float*)d_in[4];
    const float* wk     = (const float*)d_in[5];
    const float* bk     = (const float*)d_in[6];
    const float* wv     = (const float*)d_in[7];
    const float* bv     = (const float*)d_in[8];
    const float* wo     = (const float*)d_in[9];
    const float* bo     = (const float*)d_in[10];

    float* out  = (float*)d_out;                       // [B, L, D]
    float* attn = out + (size_t)NB * NL * ND;          // [B, L, H, L]

    ushort* wqT    = (ushort*)d_ws;                               // 2MB
    ushort* wkT    = wqT + (size_t)ND * NH * NDK;                 // 2MB
    ushort* wvT    = wkT + (size_t)ND * NH * NDK;                 // 0.26MB (128 rows)
    ushort* q_all  = wvT + (size_t)128 * ND;                      // 8.4MB
    ushort* k_all  = q_all + (size_t)NB * NH * NL * NDK;          // 8.4MB
    ushort* vT     = k_all + (size_t)NB * NH * NL * NDK;          // 0.5MB
    ushort* abf    = vT + (size_t)NB * NDK * NL;                  // 25.2MB (3 inputs bf16)
    ushort* heads  = abf;   // aliases abf (bf16): disjoint lifetimes

    prep_kernel<<<dim3(6672), 256, 0, stream>>>(
        query, key_in, value, wq, wk, wv, abf, wqT, wkT, wvT);
    proj_gemm<<<dim3(1088), 256, 0, stream>>>(
        abf, wqT, wkT, wvT, bq, bk, bv, q_all, k_all, vT);
    attn_mfma_kernel<<<dim3(NH, NL / 32, NB), 256, 0, stream>>>(
        q_all, k_all, vT, attn, heads);
    out_proj_kernel<<<dim3(NB * NL / 8), 256, 0, stream>>>(
        heads, wo, bo, out);
}

// Round 19
// 135.552 us; speedup vs baseline: 2.9191x; 2.9191x over previous
//
#include <hip/hip_runtime.h>
#include <math.h>

// Problem constants (B=4, L=1024, D=1024, H=16, DK=64)
#define NB 4
#define NL 1024
#define ND 1024
#define NH 16
#define NDK 64

typedef __attribute__((ext_vector_type(8))) short short8;
typedef __attribute__((ext_vector_type(4))) float f32x4;

__device__ inline ushort f2bf(float f) {
    uint x = __float_as_uint(f);
    x += 0x7FFFu + ((x >> 16) & 1u);   // RNE
    return (ushort)(x >> 16);
}
__device__ inline float bf2f(ushort u) { return __uint_as_float(((uint)u) << 16); }

__device__ inline void gload16(const void* g, void* l) {
    __builtin_amdgcn_global_load_lds(
        (const __attribute__((address_space(1))) void*)g,
        (__attribute__((address_space(3))) void*)l, 16, 0, 0);
}

// ---------------------------------------------------------------------------
// Prep: input bf16 cvt (blocks 0..6143) + weight cvt/transpose (6144..6687).
// y<16: wq; y<32: wk; y==32: wv (+zero pad); y==33: wo -> woT[n][k] bf16.
// ---------------------------------------------------------------------------
__global__ __launch_bounds__(256) void prep_kernel(
    const float* __restrict__ q, const float* __restrict__ k,
    const float* __restrict__ v,
    const float* __restrict__ wq, const float* __restrict__ wk,
    const float* __restrict__ wv, const float* __restrict__ wo,
    ushort* __restrict__ abf,
    ushort* __restrict__ wqT, ushort* __restrict__ wkT,
    ushort* __restrict__ wvT, ushort* __restrict__ woT)
{
    __shared__ ushort tl[64][72];
    const int t = threadIdx.x;
    const int bid = blockIdx.x;

    if (bid < 6144) {
        int y = bid >> 11, x = bid & 2047;
        const float* src = (y == 0) ? q : (y == 1) ? k : v;
        size_t base = ((size_t)x * 256 + t) * 8;
        float4 a = *(const float4*)(src + base);
        float4 b = *(const float4*)(src + base + 4);
        short8 o;
        o[0] = (short)f2bf(a.x); o[1] = (short)f2bf(a.y);
        o[2] = (short)f2bf(a.z); o[3] = (short)f2bf(a.w);
        o[4] = (short)f2bf(b.x); o[5] = (short)f2bf(b.y);
        o[6] = (short)f2bf(b.z); o[7] = (short)f2bf(b.w);
        *(short8*)(abf + (size_t)y * (NB * NL * ND) + base) = o;
        return;
    }

    int id = bid - 6144;
    int d0 = (id & 15) * 64;
    int y = id >> 4;

    if (y == 33) {
        // wo [64][1024] f32 -> woT [1024 n][64 k] bf16, tile n in [d0,d0+64)
        int kr = t >> 2, c0 = (t & 3) * 16;
        const float* s = wo + (size_t)kr * ND + d0 + c0;
        #pragma unroll
        for (int j = 0; j < 16; j += 4) {
            float4 vv4 = *(const float4*)(s + j);
            tl[c0 + j + 0][kr] = f2bf(vv4.x);
            tl[c0 + j + 1][kr] = f2bf(vv4.y);
            tl[c0 + j + 2][kr] = f2bf(vv4.z);
            tl[c0 + j + 3][kr] = f2bf(vv4.w);
        }
        __syncthreads();
        int vv = t >> 2, lc = (t & 3) * 16;
        ushort* d = woT + (size_t)(d0 + vv) * NDK + lc;
        #pragma unroll
        for (int j = 0; j < 16; j += 8) {
            short8 o;
            #pragma unroll
            for (int e = 0; e < 8; ++e) o[e] = (short)tl[vv][lc + j + e];
            *(short8*)(d + j) = o;
        }
        return;
    }

    const float* src; ushort* dst; int h;
    if (y < 16)      { src = wq + (size_t)y * ND * NDK;        dst = wqT; h = y; }
    else if (y < 32) { src = wk + (size_t)(y - 16) * ND * NDK; dst = wkT; h = y - 16; }
    else             { src = wv;                               dst = wvT; h = 0; }

    int r = t >> 2, c0 = (t & 3) * 16;
    const float* s = src + (size_t)(d0 + r) * NDK + c0;
    #pragma unroll
    for (int j = 0; j < 16; j += 4) {
        float4 vv4 = *(const float4*)(s + j);
        tl[c0 + j + 0][r] = f2bf(vv4.x);
        tl[c0 + j + 1][r] = f2bf(vv4.y);
        tl[c0 + j + 2][r] = f2bf(vv4.z);
        tl[c0 + j + 3][r] = f2bf(vv4.w);
    }
    __syncthreads();
    int vv = t >> 2, lc = (t & 3) * 16;
    ushort* d = dst + ((size_t)h * 64 + vv) * ND + d0 + lc;
    #pragma unroll
    for (int j = 0; j < 16; j += 8) {
        short8 o;
        #pragma unroll
        for (int e = 0; e < 8; ++e) o[e] = (short)tl[vv][lc + j + e];
        *(short8*)(d + j) = o;
    }
    if (y == 32) {
        ushort* zp = wvT + ((size_t)(64 + (t >> 2))) * ND + d0 + (t & 3) * 16;
        short8 z8 = {0,0,0,0,0,0,0,0};
        *(short8*)(zp) = z8;
        *(short8*)(zp + 8) = z8;
    }
}

// ---------------------------------------------------------------------------
// MFMA projection GEMM (exact r16). BM=64 x BN=128, BK=64, 4 waves.
// ---------------------------------------------------------------------------
__global__ __launch_bounds__(256) void proj_gemm(
    const ushort* __restrict__ abf,
    const ushort* __restrict__ wqT, const ushort* __restrict__ wkT,
    const ushort* __restrict__ wvT,
    const float* __restrict__ bq, const float* __restrict__ bk,
    const float* __restrict__ bv,
    ushort* __restrict__ q_all, ushort* __restrict__ k_all,
    ushort* __restrict__ vT)
{
    __shared__ char lds[49152];   // buf c at c*24576: A [64][64] @0, B [128][64] @8192

    int id = blockIdx.x;
    int wg = (id & 7) * 136 + (id >> 3);   // 1088 = 8 XCDs x 136, bijective
    int z, mt, nt;
    if (wg < 512)       { z = 0; mt = wg >> 3; nt = wg & 7; }
    else if (wg < 1024) { z = 1; int r2 = wg - 512; mt = r2 >> 3; nt = r2 & 7; }
    else                { z = 2; mt = wg - 1024; nt = 0; }

    const ushort* A; const ushort* Bw; const float* bias; float scale;
    if (z == 0)      { A = abf;                    Bw = wqT; bias = bq; scale = 0.125f; }
    else if (z == 1) { A = abf + NB * NL * ND;     Bw = wkT; bias = bk; scale = 1.0f; }
    else             { A = abf + 2 * NB * NL * ND; Bw = wvT; bias = bv; scale = 1.0f; }
    ushort* C = (z == 0) ? q_all : k_all;

    const int t = threadIdx.x;
    const int w = t >> 6, l = t & 63;
    const int lo16 = l & 15, hi = l >> 4;
    const int wm = w >> 1, wn = w & 1;     // wave tile: rows wm*32, cols wn*64
    const int m0 = mt * 64, n0 = nt * 128;

    f32x4 acc[2][4];
    #pragma unroll
    for (int mi = 0; mi < 2; ++mi)
        #pragma unroll
        for (int ni = 0; ni < 4; ++ni) acc[mi][ni] = (f32x4){0.f, 0.f, 0.f, 0.f};

    const int lrow = l >> 3;
    const uint lcol = ((uint)(l & 7) * 16u) ^ (((uint)lrow) << 4);

    #pragma unroll
    for (int i = 0; i < 2; ++i) {
        int s = w * 2 + i;
        gload16(A + (size_t)(m0 + s * 8 + lrow) * ND + (lcol >> 1), lds + s * 1024);
    }
    #pragma unroll
    for (int i = 0; i < 4; ++i) {
        int s = w * 4 + i;
        gload16(Bw + (size_t)(n0 + s * 8 + lrow) * ND + (lcol >> 1), lds + 8192 + s * 1024);
    }
    __syncthreads();

    int cur = 0;
    for (int kt = 0; kt < 16; ++kt) {
        if (kt < 15) {
            const int k1 = (kt + 1) * 64;
            const int nb = (cur ^ 1) * 24576;
            #pragma unroll
            for (int i = 0; i < 2; ++i) {
                int s = w * 2 + i;
                gload16(A + (size_t)(m0 + s * 8 + lrow) * ND + k1 + (lcol >> 1), lds + nb + s * 1024);
            }
            #pragma unroll
            for (int i = 0; i < 4; ++i) {
                int s = w * 4 + i;
                gload16(Bw + (size_t)(n0 + s * 8 + lrow) * ND + k1 + (lcol >> 1), lds + nb + 8192 + s * 1024);
            }
        }
        const int cb = cur * 24576;
        #pragma unroll
        for (int ks = 0; ks < 2; ++ks) {
            short8 Af[2], Bf[4];
            #pragma unroll
            for (int mi = 0; mi < 2; ++mi) {
                int row = wm * 32 + mi * 16 + lo16;
                uint off = ((uint)row * 128u + (uint)(ks * 64 + hi * 16)) ^ (((uint)(row & 7)) << 4);
                Af[mi] = *(short8*)(lds + cb + off);
            }
            #pragma unroll
            for (int ni = 0; ni < 4; ++ni) {
                int row = wn * 64 + ni * 16 + lo16;
                uint off = ((uint)row * 128u + (uint)(ks * 64 + hi * 16)) ^ (((uint)(row & 7)) << 4);
                Bf[ni] = *(short8*)(lds + cb + 8192 + off);
            }
            __builtin_amdgcn_s_setprio(1);
            #pragma unroll
            for (int mi = 0; mi < 2; ++mi)
                #pragma unroll
                for (int ni = 0; ni < 4; ++ni)
                    acc[mi][ni] = __builtin_amdgcn_mfma_f32_16x16x32_bf16(
                        Af[mi], Bf[ni], acc[mi][ni], 0, 0, 0);
            __builtin_amdgcn_s_setprio(0);
        }
        __syncthreads();   // drains vmcnt (prefetch landed) + readers done
        cur ^= 1;
    }

    // D frag: row = hi*4 + r (+16*mi), col = lo16 (+16*ni).
    if (z == 2) {
        if (wn == 0) {
            #pragma unroll
            for (int ni = 0; ni < 4; ++ni) {
                int n = ni * 16 + lo16;          // dk 0..63
                float bs = bias[n];
                #pragma unroll
                for (int mi = 0; mi < 2; ++mi) {
                    int mbase = m0 + wm * 32 + mi * 16 + hi * 4;
                    int b = mbase >> 10, ll = mbase & 1023;
                    uint u0 = (uint)f2bf(acc[mi][ni][0] + bs) | ((uint)f2bf(acc[mi][ni][1] + bs) << 16);
                    uint u1 = (uint)f2bf(acc[mi][ni][2] + bs) | ((uint)f2bf(acc[mi][ni][3] + bs) << 16);
                    *(uint2*)(vT + ((size_t)b * NDK + n) * NL + ll) = make_uint2(u0, u1);
                }
            }
        }
        return;
    }

    // z<2: restage C tile in LDS (bf16 [64][128] = 16KB), then short8 stores.
    ushort* cst = (ushort*)lds;
    const int n0w = wn * 64;
    #pragma unroll
    for (int ni = 0; ni < 4; ++ni) {
        int nl = n0w + ni * 16 + lo16;
        float bs = bias[n0 + nl];
        #pragma unroll
        for (int mi = 0; mi < 2; ++mi) {
            int mlb = wm * 32 + mi * 16 + hi * 4;
            #pragma unroll
            for (int r = 0; r < 4; ++r)
                cst[(mlb + r) * 128 + nl] = f2bf((acc[mi][ni][r] + bs) * scale);
        }
    }
    __syncthreads();
    #pragma unroll
    for (int i = 0; i < 4; ++i) {
        int unit = t + 256 * i;               // 0..1023
        int row = unit >> 4, s8 = unit & 15;
        short8 v = *(short8*)(cst + row * 128 + s8 * 8);
        int m = m0 + row, n = n0 + s8 * 8;
        int b = m >> 10, ll = m & 1023, h = n >> 6, dk = n & 63;
        *(short8*)(C + (((size_t)b * NH + h) * NL + ll) * NDK + dk) = v;
    }
}

// ---------------------------------------------------------------------------
// Stage 2: MFMA attention (exact r16: 32-row q-tile, h-major grid, nt
// interleaved writes, stride-68 pvp).
// ---------------------------------------------------------------------------
__global__ __launch_bounds__(256) void attn_mfma_kernel(
    const ushort* __restrict__ q_all, const ushort* __restrict__ k_all,
    const ushort* __restrict__ vT,
    float* __restrict__ attn, ushort* __restrict__ heads)
{
    __shared__ char raw[65536 + 640];
    float* smv  = (float*)(raw + 65536);         // [4][32]
    float* invb = (float*)(raw + 65536 + 512);   // [32]

    const int t = threadIdx.x;
    const int kh = t >> 6, l = t & 63;           // wave = k-quarter
    const int hi = l >> 4, lo = l & 15;
    const int h  = blockIdx.x;
    const int q0 = blockIdx.y * 32;
    const int b  = blockIdx.z;
    const size_t bh = ((size_t)b * NH + h) * NL;

    const int qrA = lo;            // rows 0-15 of tile
    const int qrB = 16 + lo;       // rows 16-31; (16+lo)&7 == lo&7 -> same swz
    const uint swz = ((uint)(lo & 7)) << 4;

    short8 QA0 = *(const short8*)(q_all + (bh + q0 + qrA) * NDK + hi * 8);
    short8 QA1 = *(const short8*)(q_all + (bh + q0 + qrA) * NDK + 32 + hi * 8);
    short8 QB0 = *(const short8*)(q_all + (bh + q0 + qrB) * NDK + hi * 8);
    short8 QB1 = *(const short8*)(q_all + (bh + q0 + qrB) * NDK + 32 + hi * 8);

    // ---- QK^T + exp fused: e -> LDS (bf16), sums in registers ----
    float ssumA = 0.f, ssumB = 0.f;
    for (int kt = 0; kt < 16; ++kt) {
        const int kbase = kh * 256 + kt * 16;
        short8 Ka0 = *(const short8*)(k_all + (bh + kbase + lo) * NDK + hi * 8);
        short8 Ka1 = *(const short8*)(k_all + (bh + kbase + lo) * NDK + 32 + hi * 8);
        f32x4 sA = {0.f, 0.f, 0.f, 0.f};
        f32x4 sB = {0.f, 0.f, 0.f, 0.f};
        __builtin_amdgcn_s_setprio(1);
        sA = __builtin_amdgcn_mfma_f32_16x16x32_bf16(Ka0, QA0, sA, 0, 0, 0);
        sA = __builtin_amdgcn_mfma_f32_16x16x32_bf16(Ka1, QA1, sA, 0, 0, 0);
        sB = __builtin_amdgcn_mfma_f32_16x16x32_bf16(Ka0, QB0, sB, 0, 0, 0);
        sB = __builtin_amdgcn_mfma_f32_16x16x32_bf16(Ka1, QB1, sB, 0, 0, 0);
        __builtin_amdgcn_s_setprio(0);
        float a0 = __expf(sA[0]), a1 = __expf(sA[1]);
        float a2 = __expf(sA[2]), a3 = __expf(sA[3]);
        float b0 = __expf(sB[0]), b1 = __expf(sB[1]);
        float b2 = __expf(sB[2]), b3 = __expf(sB[3]);
        ssumA += (a0 + a1) + (a2 + a3);
        ssumB += (b0 + b1) + (b2 + b3);
        uint colb = (((uint)(kbase + hi * 4)) * 2u) ^ swz;
        *(uint2*)(raw + (uint)qrA * 2048u + colb) =
            make_uint2((uint)f2bf(a0) | ((uint)f2bf(a1) << 16),
                       (uint)f2bf(a2) | ((uint)f2bf(a3) << 16));
        *(uint2*)(raw + (uint)qrB * 2048u + colb) =
            make_uint2((uint)f2bf(b0) | ((uint)f2bf(b1) << 16),
                       (uint)f2bf(b2) | ((uint)f2bf(b3) << 16));
    }
    ssumA += __shfl_xor(ssumA, 16);
    ssumA += __shfl_xor(ssumA, 32);
    ssumB += __shfl_xor(ssumB, 16);
    ssumB += __shfl_xor(ssumB, 32);
    if (l < 16) {
        smv[kh * 32 + l]      = ssumA;
        smv[kh * 32 + 16 + l] = ssumB;
    }
    __syncthreads();
    if (t < 32) invb[t] = 1.0f / (smv[t] + smv[32 + t] + smv[64 + t] + smv[96 + t]);
    __syncthreads();

    // ---- PV with interleaved attn-row nt writes (4 rows per kc iter) ----
    f32x4 accA0 = {0.f,0.f,0.f,0.f}, accA1 = {0.f,0.f,0.f,0.f};
    f32x4 accA2 = {0.f,0.f,0.f,0.f}, accA3 = {0.f,0.f,0.f,0.f};
    f32x4 accB0 = {0.f,0.f,0.f,0.f}, accB1 = {0.f,0.f,0.f,0.f};
    f32x4 accB2 = {0.f,0.f,0.f,0.f}, accB3 = {0.f,0.f,0.f,0.f};
    for (int kc = 0; kc < 8; ++kc) {
        const int kchunk = kh * 256 + kc * 32;
        uint colb = (((uint)(kchunk + hi * 8)) * 2u) ^ swz;
        short8 paA = *(short8*)(raw + (uint)qrA * 2048u + colb);
        short8 paB = *(short8*)(raw + (uint)qrB * 2048u + colb);
        short8 b0 = *(const short8*)(vT + ((size_t)(b * NDK +  0 + lo)) * NL + kchunk + hi * 8);
        short8 b1 = *(const short8*)(vT + ((size_t)(b * NDK + 16 + lo)) * NL + kchunk + hi * 8);
        short8 b2 = *(const short8*)(vT + ((size_t)(b * NDK + 32 + lo)) * NL + kchunk + hi * 8);
        short8 b3 = *(const short8*)(vT + ((size_t)(b * NDK + 48 + lo)) * NL + kchunk + hi * 8);
        __builtin_amdgcn_s_setprio(1);
        accA0 = __builtin_amdgcn_mfma_f32_16x16x32_bf16(paA, b0, accA0, 0, 0, 0);
        accA1 = __builtin_amdgcn_mfma_f32_16x16x32_bf16(paA, b1, accA1, 0, 0, 0);
        accA2 = __builtin_amdgcn_mfma_f32_16x16x32_bf16(paA, b2, accA2, 0, 0, 0);
        accA3 = __builtin_amdgcn_mfma_f32_16x16x32_bf16(paA, b3, accA3, 0, 0, 0);
        accB0 = __builtin_amdgcn_mfma_f32_16x16x32_bf16(paB, b0, accB0, 0, 0, 0);
        accB1 = __builtin_amdgcn_mfma_f32_16x16x32_bf16(paB, b1, accB1, 0, 0, 0);
        accB2 = __builtin_amdgcn_mfma_f32_16x16x32_bf16(paB, b2, accB2, 0, 0, 0);
        accB3 = __builtin_amdgcn_mfma_f32_16x16x32_bf16(paB, b3, accB3, 0, 0, 0);
        __builtin_amdgcn_s_setprio(0);
        // independent of the MFMAs above: stream 4 normalized attn rows
        #pragma unroll
        for (int rj = 0; rj < 4; ++rj) {
            int rr = kc * 4 + rj;
            uint byteoff = (uint)rr * 2048u + (((uint)t * 8u) ^ (((uint)(rr & 7)) << 4));
            uint2 v = *(uint2*)(raw + byteoff);
            float inv = invb[rr];
            f32x4 o;
            o[0] = bf2f((ushort)(v.x & 0xFFFF)) * inv;
            o[1] = bf2f((ushort)(v.x >> 16)) * inv;
            o[2] = bf2f((ushort)(v.y & 0xFFFF)) * inv;
            o[3] = bf2f((ushort)(v.y >> 16)) * inv;
            __builtin_nontemporal_store(o,
                (f32x4*)(attn + (((size_t)b * NL + q0 + rr) * NH + h) * NL + (size_t)t * 4));
        }
    }
    __syncthreads();   // all waves done READING e before aliasing writes
    float* pvp = (float*)raw;   // [4 kh][32 q] rows, stride 68 words (34.8KB)
    #pragma unroll
    for (int r = 0; r < 4; ++r) {
        int rowA = kh * 32 + hi * 4 + r;
        pvp[rowA * 68 +  0 + lo] = accA0[r];
        pvp[rowA * 68 + 16 + lo] = accA1[r];
        pvp[rowA * 68 + 32 + lo] = accA2[r];
        pvp[rowA * 68 + 48 + lo] = accA3[r];
        int rowB = rowA + 16;
        pvp[rowB * 68 +  0 + lo] = accB0[r];
        pvp[rowB * 68 + 16 + lo] = accB1[r];
        pvp[rowB * 68 + 32 + lo] = accB2[r];
        pvp[rowB * 68 + 48 + lo] = accB3[r];
    }
    __syncthreads();
    #pragma unroll
    for (int i = 0; i < 8; ++i) {
        int idx = t + 256 * i;              // 0..2047 = qq*64 + vv
        int qq = idx >> 6, vv = idx & 63;
        float s4 = pvp[qq * 68 + vv] + pvp[(32 + qq) * 68 + vv]
                 + pvp[(64 + qq) * 68 + vv] + pvp[(96 + qq) * 68 + vv];
        heads[(bh + q0 + qq) * NDK + vv] = f2bf(s4 * invb[qq]);
    }
}

// ---------------------------------------------------------------------------
// Stage 3: MFMA output projection. Block = 32 rows x 256 cols (grid 512).
// hm bf16 [32][64] in swizzled LDS (mean over 16 heads, f32 accum), then
// A-frags from LDS + B-frags from woT[n][k]; f32 stores + bias.
// ---------------------------------------------------------------------------
__global__ __launch_bounds__(256) void out_proj_kernel(
    const ushort* __restrict__ heads, const ushort* __restrict__ woT,
    const float* __restrict__ bo, float* __restrict__ out)
{
    __shared__ char lds[4096];   // hm bf16 [32 rows][64 k], swizzled rows of 128B
    const int t = threadIdx.x;
    const int w = t >> 6, l = t & 63;
    const int lo16 = l & 15, hi = l >> 4;
    const int rt = blockIdx.x >> 2, ct = blockIdx.x & 3;
    const int m0 = rt * 32, n0 = ct * 256;
    const int b = m0 >> 10, l0 = m0 & 1023;

    // hm: thread owns (row r, dk-octet qd)
    {
        int r = t >> 3, qd = t & 7;
        float s[8] = {0.f,0.f,0.f,0.f,0.f,0.f,0.f,0.f};
        #pragma unroll
        for (int h = 0; h < 16; ++h) {
            uint4 v = *(const uint4*)&heads[(((size_t)b * NH + h) * NL + l0 + r) * NDK + qd * 8];
            s[0] += bf2f((ushort)(v.x & 0xFFFF)); s[1] += bf2f((ushort)(v.x >> 16));
            s[2] += bf2f((ushort)(v.y & 0xFFFF)); s[3] += bf2f((ushort)(v.y >> 16));
            s[4] += bf2f((ushort)(v.z & 0xFFFF)); s[5] += bf2f((ushort)(v.z >> 16));
            s[6] += bf2f((ushort)(v.w & 0xFFFF)); s[7] += bf2f((ushort)(v.w >> 16));
        }
        short8 o;
        #pragma unroll
        for (int e = 0; e < 8; ++e) o[e] = (short)f2bf(s[e] * 0.0625f);
        uint off = ((uint)r * 128u + (uint)qd * 16u) ^ (((uint)(r & 7)) << 4);
        *(short8*)(lds + off) = o;
    }
    __syncthreads();

    // MFMA: wave w -> rows (w&1)*16, cols (w>>1)*128
    const int wr = (w & 1) * 16, wc = (w >> 1) * 128;
    short8 Af[2];
    {
        int row = wr + lo16;
        #pragma unroll
        for (int ks = 0; ks < 2; ++ks) {
            uint off = ((uint)row * 128u + (uint)(ks * 64 + hi * 16)) ^ (((uint)(row & 7)) << 4);
            Af[ks] = *(short8*)(lds + off);
        }
    }
    f32x4 acc[8];
    #pragma unroll
    for (int ni = 0; ni < 8; ++ni) acc[ni] = (f32x4){0.f, 0.f, 0.f, 0.f};
    #pragma unroll
    for (int ni = 0; ni < 8; ++ni) {
        int n = n0 + wc + ni * 16 + lo16;
        short8 B0 = *(const short8*)(woT + (size_t)n * NDK + hi * 8);
        short8 B1 = *(const short8*)(woT + (size_t)n * NDK + 32 + hi * 8);
        acc[ni] = __builtin_amdgcn_mfma_f32_16x16x32_bf16(Af[0], B0, acc[ni], 0, 0, 0);
        acc[ni] = __builtin_amdgcn_mfma_f32_16x16x32_bf16(Af[1], B1, acc[ni], 0, 0, 0);
    }
    #pragma unroll
    for (int ni = 0; ni < 8; ++ni) {
        int n = n0 + wc + ni * 16 + lo16;
        float bs = bo[n];
        #pragma unroll
        for (int r = 0; r < 4; ++r) {
            int m = m0 + wr + hi * 4 + r;
            out[(size_t)m * ND + n] = acc[ni][r] + bs;
        }
    }
}

// ---------------------------------------------------------------------------
extern "C" void kernel_launch(void* const* d_in, const int* in_sizes, int n_in,
                              void* d_out, int out_size, void* d_ws, size_t ws_size,
                              hipStream_t stream) {
    const float* query  = (const float*)d_in[0];
    const float* key_in = (const float*)d_in[1];
    const float* value  = (const float*)d_in[2];
    const float* wq     = (const float*)d_in[3];
    const float* bq     = (const float*)d_in[4];
    const float* wk     = (const float*)d_in[5];
    const float* bk     = (const float*)d_in[6];
    const float* wv     = (const float*)d_in[7];
    const float* bv     = (const float*)d_in[8];
    const float* wo     = (const float*)d_in[9];
    const float* bo     = (const float*)d_in[10];

    float* out  = (float*)d_out;                       // [B, L, D]
    float* attn = out + (size_t)NB * NL * ND;          // [B, L, H, L]

    ushort* wqT    = (ushort*)d_ws;                               // 2MB
    ushort* wkT    = wqT + (size_t)ND * NH * NDK;                 // 2MB
    ushort* wvT    = wkT + (size_t)ND * NH * NDK;                 // 0.26MB (128 rows)
    ushort* woT    = wvT + (size_t)128 * ND;                      // 0.13MB [1024][64]
    ushort* q_all  = woT + (size_t)ND * NDK;                      // 8.4MB
    ushort* k_all  = q_all + (size_t)NB * NH * NL * NDK;          // 8.4MB
    ushort* vT     = k_all + (size_t)NB * NH * NL * NDK;          // 0.5MB
    ushort* abf    = vT + (size_t)NB * NDK * NL;                  // 25.2MB (3 inputs bf16)
    ushort* heads  = abf;   // aliases abf (bf16): disjoint lifetimes

    prep_kernel<<<dim3(6688), 256, 0, stream>>>(
        query, key_in, value, wq, wk, wv, wo, abf, wqT, wkT, wvT, woT);
    proj_gemm<<<dim3(1088), 256, 0, stream>>>(
        abf, wqT, wkT, wvT, bq, bk, bv, q_all, k_all, vT);
    attn_mfma_kernel<<<dim3(NH, NL / 32, NB), 256, 0, stream>>>(
        q_all, k_all, vT, attn, heads);
    out_proj_kernel<<<dim3(512), 256, 0, stream>>>(
        heads, woT, bo, out);
}